// Round 1
// 1426.305 us; speedup vs baseline: 3.5091x; 3.5091x over previous
//
#include <hip/hip_runtime.h>

typedef unsigned short u16;
typedef __attribute__((ext_vector_type(8))) short short8;
typedef __attribute__((ext_vector_type(4))) float f32x4;
typedef __attribute__((ext_vector_type(8))) __bf16 bf16x8;

__device__ __forceinline__ float b2f(u16 u) {
  unsigned int i = ((unsigned int)u) << 16;
  return __builtin_bit_cast(float, i);
}
__device__ __forceinline__ u16 f2b(float f) {
  unsigned int i = __builtin_bit_cast(unsigned int, f);
  i += 0x7fffu + ((i >> 16) & 1u);   // RNE
  return (u16)(i >> 16);
}

// ---------------------------------------------------------------------------
// K0: fp32 -> bf16 conversion, 8 elements/thread, memory-bound.
// ---------------------------------------------------------------------------
__global__ __launch_bounds__(256) void cvt_bf16(const float* __restrict__ in,
                                                u16* __restrict__ out, int n8) {
  int i = blockIdx.x * 256 + threadIdx.x;
  if (i >= n8) return;
  f32x4 v0 = *(const f32x4*)(in + (size_t)i * 8);
  f32x4 v1 = *(const f32x4*)(in + (size_t)i * 8 + 4);
  short8 o;
  o[0] = (short)f2b(v0.x); o[1] = (short)f2b(v0.y);
  o[2] = (short)f2b(v0.z); o[3] = (short)f2b(v0.w);
  o[4] = (short)f2b(v1.x); o[5] = (short)f2b(v1.y);
  o[6] = (short)f2b(v1.z); o[7] = (short)f2b(v1.w);
  *(short8*)(out + (size_t)i * 8) = o;
}

// ---------------------------------------------------------------------------
// K1: KV projection as bf16 MFMA GEMM (m97 structure: 128x128 tile, BK=32,
// 4 waves x (64x64) sub-tiles, 4x4 frags of mfma_f32_16x16x32_bf16,
// global_load_lds(16B) staging into linear LDS, 2-barrier K-loop).
// C[M=nb*8192][N=1536] = Xbf @ Wbf^T, fp32 accum, stored bf16 into
// KV[kv=2][bl][h=12][s=8192][d=64].
// ---------------------------------------------------------------------------
__global__ __launch_bounds__(256) void kv_gemm_mfma(const u16* __restrict__ A,
                                                    const u16* __restrict__ B,
                                                    u16* __restrict__ KV, int nb) {
  __shared__ u16 As[128 * 32];   // [row][k] linear, 8 KB
  __shared__ u16 Bs[128 * 32];
  const int tid = threadIdx.x;
  const int lane = tid & 63;
  const int w = tid >> 6;              // wave 0..3
  const int wr = w >> 1, wc = w & 1;   // wave -> 64x64 quadrant
  const int fr = lane & 15;            // fragment row/col
  const int fq = lane >> 4;            // k-chunk 0..3
  const int bid = blockIdx.x;
  const int nt = bid % 12, mt = bid / 12;
  const int m0 = mt * 128, n0 = nt * 128;

  f32x4 acc[4][4] = {};

  for (int k0 = 0; k0 < 768; k0 += 32) {
    // stage A,B tiles: 512 chunks of 16B each; wave w owns chunks
    // [w*128, w*128+128). LDS dest must be linear in lane (G_load_lds rule).
#pragma unroll
    for (int i = 0; i < 2; ++i) {
      int c = w * 128 + i * 64 + lane;
      int row = c >> 2, q = c & 3;                 // 4 chunks per 64B row
      const u16* ga = A + (size_t)(m0 + row) * 768 + k0 + q * 8;
      const u16* gb = B + (size_t)(n0 + row) * 768 + k0 + q * 8;
      __builtin_amdgcn_global_load_lds(
          (const __attribute__((address_space(1))) void*)ga,
          (__attribute__((address_space(3))) void*)(As + (size_t)(w * 128 + i * 64) * 8),
          16, 0, 0);
      __builtin_amdgcn_global_load_lds(
          (const __attribute__((address_space(1))) void*)gb,
          (__attribute__((address_space(3))) void*)(Bs + (size_t)(w * 128 + i * 64) * 8),
          16, 0, 0);
    }
    __syncthreads();   // compiler drains vmcnt before s_barrier

    bf16x8 a[4], b[4];
#pragma unroll
    for (int m = 0; m < 4; ++m)
      a[m] = *(const bf16x8*)(As + (size_t)(wr * 64 + m * 16 + fr) * 32 + fq * 8);
#pragma unroll
    for (int n = 0; n < 4; ++n)
      b[n] = *(const bf16x8*)(Bs + (size_t)(wc * 64 + n * 16 + fr) * 32 + fq * 8);
#pragma unroll
    for (int m = 0; m < 4; ++m)
#pragma unroll
      for (int n = 0; n < 4; ++n)
        acc[m][n] = __builtin_amdgcn_mfma_f32_16x16x32_bf16(a[m], b[n], acc[m][n], 0, 0, 0);
    __syncthreads();
  }

  // Epilogue. C/D layout (verified m89/m91): col = lane&15, row = (lane>>4)*4 + j.
  const int bl = m0 >> 13;           // 8192 % 128 == 0 -> constant per block
  const int sbase = (m0 & 8191) + wr * 64 + fq * 4;
#pragma unroll
  for (int n = 0; n < 4; ++n) {
    int f = n0 + wc * 64 + n * 16 + fr;
    int kvsel = f >= 768 ? 1 : 0;
    int h = (f >> 6) - kvsel * 12;
    int d = f & 63;
    u16* outp = KV + ((size_t)(kvsel * nb + bl) * 12 + h) * (8192 * 64) + d;
#pragma unroll
    for (int m = 0; m < 4; ++m) {
      int s = sbase + m * 16;
#pragma unroll
      for (int j = 0; j < 4; ++j)
        outp[(size_t)(s + j) * 64] = f2b(acc[m][n][j]);
    }
  }
}

// ---------------------------------------------------------------------------
// K2: Q projection (fp32), scale 0.125 folded in. (unchanged)
// ---------------------------------------------------------------------------
__global__ __launch_bounds__(256) void q_proj(const float* __restrict__ X,
                                              const float* __restrict__ Wq,
                                              float* __restrict__ Q) {
  __shared__ float xs[768];
  const int bid = blockIdx.x;
  const int rrow = bid / 3, cg = bid % 3;
  const int b = rrow >> 2, s = rrow & 3;
  const float* xrow = X + ((size_t)b * 8192 + s) * 768;
  const int t = threadIdx.x;
  if (t < 192) *(f32x4*)&xs[t * 4] = *(const f32x4*)(xrow + t * 4);
  __syncthreads();
  const int c = cg * 256 + t;
  const float* wrow = Wq + (size_t)c * 768;
  float acc = 0.f;
#pragma unroll 8
  for (int jj = 0; jj < 192; ++jj) {
    f32x4 v = *(const f32x4*)(wrow + jj * 4);
    acc += v.x * xs[jj * 4] + v.y * xs[jj * 4 + 1] + v.z * xs[jj * 4 + 2] +
           v.w * xs[jj * 4 + 3];
  }
  Q[(size_t)rrow * 768 + c] = acc * 0.125f;
}

// ---------------------------------------------------------------------------
// K3: textbook attention, full softmax in LDS. (unchanged)
// ---------------------------------------------------------------------------
__global__ __launch_bounds__(256) void attn_simple(const u16* __restrict__ KV,
                                                   const float* __restrict__ Q,
                                                   float* __restrict__ Att,
                                                   int b0, int nb) {
  __shared__ float sc[8192];
  __shared__ float red[256];
  __shared__ float qsh[64];
  __shared__ float osum[4][64];
  const int tid = threadIdx.x;
  const int bid = blockIdx.x;
  const int x = bid & 3;
  const int rem = bid >> 2;
  const int h = rem % 12, bl = rem / 12;
  const int b = b0 + bl;

  if (tid < 64) qsh[tid] = Q[(size_t)(b * 4 + x) * 768 + h * 64 + tid];
  __syncthreads();

  const u16* Kb = KV + (size_t)(bl * 12 + h) * (8192 * 64);
  const u16* Vb = KV + (size_t)((nb + bl) * 12 + h) * (8192 * 64);

  float lmax = -__builtin_inff();
  for (int y = tid; y < 8192; y += 256) {
    const u16* kr = Kb + (size_t)y * 64;
    float s = 0.f;
#pragma unroll
    for (int jj = 0; jj < 8; ++jj) {
      short8 k8 = *(const short8*)(kr + jj * 8);
#pragma unroll
      for (int e = 0; e < 8; ++e) s += b2f((u16)k8[e]) * qsh[jj * 8 + e];
    }
    sc[y] = s;
    lmax = fmaxf(lmax, s);
  }
  red[tid] = lmax;
  __syncthreads();
  for (int off = 128; off; off >>= 1) {
    if (tid < off) red[tid] = fmaxf(red[tid], red[tid + off]);
    __syncthreads();
  }
  const float M = red[0];
  __syncthreads();

  float lsum = 0.f;
  for (int y = tid; y < 8192; y += 256) {
    float p = __expf(sc[y] - M);
    sc[y] = p;
    lsum += p;
  }
  red[tid] = lsum;
  __syncthreads();
  for (int off = 128; off; off >>= 1) {
    if (tid < off) red[tid] += red[tid + off];
    __syncthreads();
  }
  const float L = red[0];

  const int g = tid >> 6, d = tid & 63;
  float o = 0.f;
  for (int y = g; y < 8192; y += 4) o += sc[y] * b2f(Vb[(size_t)y * 64 + d]);
  osum[g][d] = o;
  __syncthreads();
  if (tid < 64) {
    float t = osum[0][tid] + osum[1][tid] + osum[2][tid] + osum[3][tid];
    Att[(size_t)(b * 4 + x) * 768 + h * 64 + tid] = t / L;
  }
}

// ---------------------------------------------------------------------------
// K4: output projection + bias, fp32 output. (unchanged)
// ---------------------------------------------------------------------------
__global__ __launch_bounds__(256) void out_proj(const float* __restrict__ Att,
                                               const float* __restrict__ Wo,
                                               const float* __restrict__ Bo,
                                               float* __restrict__ Out) {
  __shared__ float xs[768];
  const int bid = blockIdx.x;
  const int rrow = bid / 3, cg = bid % 3;
  const int t = threadIdx.x;
  if (t < 192) *(f32x4*)&xs[t * 4] = *(const f32x4*)(Att + (size_t)rrow * 768 + t * 4);
  __syncthreads();
  const int c = cg * 256 + t;
  const float* wrow = Wo + (size_t)c * 768;
  float acc = 0.f;
#pragma unroll 8
  for (int jj = 0; jj < 192; ++jj) {
    f32x4 v = *(const f32x4*)(wrow + jj * 4);
    acc += v.x * xs[jj * 4] + v.y * xs[jj * 4 + 1] + v.z * xs[jj * 4 + 2] +
           v.w * xs[jj * 4 + 3];
  }
  acc += Bo[c];
  Out[(size_t)rrow * 768 + c] = acc;
}

// ---------------------------------------------------------------------------
extern "C" void kernel_launch(void* const* d_in, const int* in_sizes, int n_in,
                              void* d_out, int out_size, void* d_ws, size_t ws_size,
                              hipStream_t stream) {
  const float* X = (const float*)d_in[0];    // [8,8192,768] fp32
  const float* Wkv = (const float*)d_in[1];  // [1536,768] fp32
  const float* Wq = (const float*)d_in[2];   // [768,768] fp32
  const float* Wo = (const float*)d_in[3];   // [768,768] fp32
  const float* Bo = (const float*)d_in[4];   // [768] fp32
  float* Out = (float*)d_out;                // [8,4,768] fp32

  char* ws = (char*)d_ws;
  float* Q = (float*)ws;                          //  98,304 B
  float* Att = (float*)(ws + 98304);              //  98,304 B
  u16* Wbf = (u16*)(ws + 196608);                 //  2,359,296 B
  u16* Xbf = (u16*)(ws + 196608 + 2359296);       //  100,663,296 B (full X, bf16)
  const size_t tail = 196608 + 2359296 + 100663296ull;  // 103,219,200 B
  const size_t kvPerBatch = 2ull * 12 * 8192 * 64 * 2;  // 25,165,824 B

  int nb = 8;
  while (nb > 1 && tail + (size_t)nb * kvPerBatch > ws_size) nb >>= 1;
  const int groups = 8 / nb;
  u16* KV = (u16*)(ws + tail);

  // weight + activation conversion to bf16 (once)
  hipLaunchKernelGGL(cvt_bf16, dim3(576), dim3(256), 0, stream, Wkv, Wbf,
                     1536 * 768 / 8);
  hipLaunchKernelGGL(cvt_bf16, dim3(24576), dim3(256), 0, stream, X, Xbf,
                     8 * 8192 * 768 / 8);
  hipLaunchKernelGGL(q_proj, dim3(96), dim3(256), 0, stream, X, Wq, Q);

  for (int g = 0; g < groups; ++g) {
    const int b0 = g * nb;
    hipLaunchKernelGGL(kv_gemm_mfma, dim3(nb * 768), dim3(256), 0, stream,
                       Xbf + (size_t)b0 * 8192 * 768, Wbf, KV, nb);
    hipLaunchKernelGGL(attn_simple, dim3(nb * 48), dim3(256), 0, stream,
                       KV, Q, Att, b0, nb);
  }
  hipLaunchKernelGGL(out_proj, dim3(96), dim3(256), 0, stream, Att, Wo, Bo, Out);
}

// Round 2
// 648.751 us; speedup vs baseline: 7.7150x; 2.1985x over previous
//
#include <hip/hip_runtime.h>

typedef unsigned short u16;
typedef __attribute__((ext_vector_type(8))) short short8;
typedef __attribute__((ext_vector_type(4))) float f32x4;
typedef __attribute__((ext_vector_type(8))) __bf16 bf16x8;

__device__ __forceinline__ float b2f(u16 u) {
  unsigned int i = ((unsigned int)u) << 16;
  return __builtin_bit_cast(float, i);
}
__device__ __forceinline__ u16 f2b(float f) {
  unsigned int i = __builtin_bit_cast(unsigned int, f);
  i += 0x7fffu + ((i >> 16) & 1u);   // RNE
  return (u16)(i >> 16);
}

// ---------------------------------------------------------------------------
// K0: fp32 -> bf16 conversion. (unchanged)
// ---------------------------------------------------------------------------
__global__ __launch_bounds__(256) void cvt_bf16(const float* __restrict__ in,
                                                u16* __restrict__ out, int n8) {
  int i = blockIdx.x * 256 + threadIdx.x;
  if (i >= n8) return;
  f32x4 v0 = *(const f32x4*)(in + (size_t)i * 8);
  f32x4 v1 = *(const f32x4*)(in + (size_t)i * 8 + 4);
  short8 o;
  o[0] = (short)f2b(v0.x); o[1] = (short)f2b(v0.y);
  o[2] = (short)f2b(v0.z); o[3] = (short)f2b(v0.w);
  o[4] = (short)f2b(v1.x); o[5] = (short)f2b(v1.y);
  o[6] = (short)f2b(v1.z); o[7] = (short)f2b(v1.w);
  *(short8*)(out + (size_t)i * 8) = o;
}

// ---------------------------------------------------------------------------
// K1: KV projection bf16 MFMA GEMM. (unchanged from round 1)
// ---------------------------------------------------------------------------
__global__ __launch_bounds__(256) void kv_gemm_mfma(const u16* __restrict__ A,
                                                    const u16* __restrict__ B,
                                                    u16* __restrict__ KV, int nb) {
  __shared__ u16 As[128 * 32];
  __shared__ u16 Bs[128 * 32];
  const int tid = threadIdx.x;
  const int lane = tid & 63;
  const int w = tid >> 6;
  const int wr = w >> 1, wc = w & 1;
  const int fr = lane & 15;
  const int fq = lane >> 4;
  const int bid = blockIdx.x;
  const int nt = bid % 12, mt = bid / 12;
  const int m0 = mt * 128, n0 = nt * 128;

  f32x4 acc[4][4] = {};

  for (int k0 = 0; k0 < 768; k0 += 32) {
#pragma unroll
    for (int i = 0; i < 2; ++i) {
      int c = w * 128 + i * 64 + lane;
      int row = c >> 2, q = c & 3;
      const u16* ga = A + (size_t)(m0 + row) * 768 + k0 + q * 8;
      const u16* gb = B + (size_t)(n0 + row) * 768 + k0 + q * 8;
      __builtin_amdgcn_global_load_lds(
          (const __attribute__((address_space(1))) void*)ga,
          (__attribute__((address_space(3))) void*)(As + (size_t)(w * 128 + i * 64) * 8),
          16, 0, 0);
      __builtin_amdgcn_global_load_lds(
          (const __attribute__((address_space(1))) void*)gb,
          (__attribute__((address_space(3))) void*)(Bs + (size_t)(w * 128 + i * 64) * 8),
          16, 0, 0);
    }
    __syncthreads();

    bf16x8 a[4], b[4];
#pragma unroll
    for (int m = 0; m < 4; ++m)
      a[m] = *(const bf16x8*)(As + (size_t)(wr * 64 + m * 16 + fr) * 32 + fq * 8);
#pragma unroll
    for (int n = 0; n < 4; ++n)
      b[n] = *(const bf16x8*)(Bs + (size_t)(wc * 64 + n * 16 + fr) * 32 + fq * 8);
#pragma unroll
    for (int m = 0; m < 4; ++m)
#pragma unroll
      for (int n = 0; n < 4; ++n)
        acc[m][n] = __builtin_amdgcn_mfma_f32_16x16x32_bf16(a[m], b[n], acc[m][n], 0, 0, 0);
    __syncthreads();
  }

  const int bl = m0 >> 13;
  const int sbase = (m0 & 8191) + wr * 64 + fq * 4;
#pragma unroll
  for (int n = 0; n < 4; ++n) {
    int f = n0 + wc * 64 + n * 16 + fr;
    int kvsel = f >= 768 ? 1 : 0;
    int h = (f >> 6) - kvsel * 12;
    int d = f & 63;
    u16* outp = KV + ((size_t)(kvsel * nb + bl) * 12 + h) * (8192 * 64) + d;
#pragma unroll
    for (int m = 0; m < 4; ++m) {
      int s = sbase + m * 16;
#pragma unroll
      for (int j = 0; j < 4; ++j)
        outp[(size_t)(s + j) * 64] = f2b(acc[m][n][j]);
    }
  }
}

// ---------------------------------------------------------------------------
// K2: Q projection (fp32), scale 0.125 folded in. (unchanged)
// ---------------------------------------------------------------------------
__global__ __launch_bounds__(256) void q_proj(const float* __restrict__ X,
                                              const float* __restrict__ Wq,
                                              float* __restrict__ Q) {
  __shared__ float xs[768];
  const int bid = blockIdx.x;
  const int rrow = bid / 3, cg = bid % 3;
  const int b = rrow >> 2, s = rrow & 3;
  const float* xrow = X + ((size_t)b * 8192 + s) * 768;
  const int t = threadIdx.x;
  if (t < 192) *(f32x4*)&xs[t * 4] = *(const f32x4*)(xrow + t * 4);
  __syncthreads();
  const int c = cg * 256 + t;
  const float* wrow = Wq + (size_t)c * 768;
  float acc = 0.f;
#pragma unroll 8
  for (int jj = 0; jj < 192; ++jj) {
    f32x4 v = *(const f32x4*)(wrow + jj * 4);
    acc += v.x * xs[jj * 4] + v.y * xs[jj * 4 + 1] + v.z * xs[jj * 4 + 2] +
           v.w * xs[jj * 4 + 3];
  }
  Q[(size_t)rrow * 768 + c] = acc * 0.125f;
}

// ---------------------------------------------------------------------------
// K3a: split-S attention partials. grid = nb*12*32, block 256.
// Each block: one (bl, h, chunk of 256 S-positions). Reads K-chunk ONCE for
// all 4 queries, computes chunk-local softmax partials (m, l) and partial
// PV output. Flash-decode combine in K3b.
// ---------------------------------------------------------------------------
#define CHUNK 256
#define NSCH 32

__global__ __launch_bounds__(256) void attn_part(const u16* __restrict__ KV,
                                                 const float* __restrict__ Q,
                                                 float* __restrict__ Mp,
                                                 float* __restrict__ Lp,
                                                 float* __restrict__ Op,
                                                 int b0, int nb) {
  __shared__ float qsh[4][64];
  __shared__ float sc[4][CHUNK];
  const int tid = threadIdx.x;
  const int bid = blockIdx.x;
  const int ch = bid % NSCH;
  const int rem = bid / NSCH;
  const int h = rem % 12, bl = rem / 12;
  const int b = b0 + bl;

  // load Q for all 4 queries of this (b,h)
  qsh[tid >> 6][tid & 63] = Q[(size_t)(b * 4 + (tid >> 6)) * 768 + h * 64 + (tid & 63)];
  __syncthreads();

  const u16* Kb = KV + (size_t)(bl * 12 + h) * (8192 * 64) + (size_t)ch * CHUNK * 64;
  const u16* Vb = KV + (size_t)((nb + bl) * 12 + h) * (8192 * 64) + (size_t)ch * CHUNK * 64;

  // QK^T: thread tid owns position y = tid; K row read once, 4 dots.
  {
    const u16* kr = Kb + (size_t)tid * 64;
    float s0 = 0.f, s1 = 0.f, s2 = 0.f, s3 = 0.f;
#pragma unroll
    for (int jj = 0; jj < 8; ++jj) {
      short8 k8 = *(const short8*)(kr + jj * 8);
#pragma unroll
      for (int e = 0; e < 8; ++e) {
        float kv = b2f((u16)k8[e]);
        s0 += kv * qsh[0][jj * 8 + e];
        s1 += kv * qsh[1][jj * 8 + e];
        s2 += kv * qsh[2][jj * 8 + e];
        s3 += kv * qsh[3][jj * 8 + e];
      }
    }
    sc[0][tid] = s0; sc[1][tid] = s1; sc[2][tid] = s2; sc[3][tid] = s3;
  }
  __syncthreads();

  // chunk-local softmax for x = group g; partials written by lane 0.
  const int g = tid >> 6, lane = tid & 63;
  const int pidx = (((bl * 12 + h) * 4 + g) * NSCH) + ch;
  {
    float m4 = fmaxf(fmaxf(sc[g][lane], sc[g][lane + 64]),
                     fmaxf(sc[g][lane + 128], sc[g][lane + 192]));
#pragma unroll
    for (int off = 32; off; off >>= 1) m4 = fmaxf(m4, __shfl_xor(m4, off));
    float ls = 0.f;
#pragma unroll
    for (int i = 0; i < 4; ++i) {
      int y = lane + i * 64;
      float p = __expf(sc[g][y] - m4);
      sc[g][y] = p;
      ls += p;
    }
#pragma unroll
    for (int off = 32; off; off >>= 1) ls += __shfl_xor(ls, off);
    if (lane == 0) { Mp[pidx] = m4; Lp[pidx] = ls; }
  }
  __syncthreads();

  // partial PV: thread (x=g, d=lane): o = sum_y p[x][y] * V[y][d]
  {
    float o = 0.f;
#pragma unroll 8
    for (int y = 0; y < CHUNK; ++y)
      o += sc[g][y] * b2f(Vb[(size_t)y * 64 + lane]);
    Op[(size_t)pidx * 64 + lane] = o;
  }
}

// ---------------------------------------------------------------------------
// K3b: combine chunk partials. grid = nb*48, block 64.
// ---------------------------------------------------------------------------
__global__ __launch_bounds__(64) void attn_combine(const float* __restrict__ Mp,
                                                   const float* __restrict__ Lp,
                                                   const float* __restrict__ Op,
                                                   float* __restrict__ Att,
                                                   int b0) {
  const int p = blockIdx.x;            // (bl*12+h)*4 + x
  const int d = threadIdx.x;
  const int x = p & 3;
  const int h = (p >> 2) % 12;
  const int bl = p / 48;

  float M = -__builtin_inff();
#pragma unroll 8
  for (int ch = 0; ch < NSCH; ++ch) M = fmaxf(M, Mp[p * NSCH + ch]);
  float L = 0.f, O = 0.f;
#pragma unroll 8
  for (int ch = 0; ch < NSCH; ++ch) {
    float w = __expf(Mp[p * NSCH + ch] - M);
    L += Lp[p * NSCH + ch] * w;
    O += Op[(size_t)(p * NSCH + ch) * 64 + d] * w;
  }
  Att[(size_t)((b0 + bl) * 4 + x) * 768 + h * 64 + d] = O / L;
}

// ---------------------------------------------------------------------------
// K4: output projection + bias, fp32 output. (unchanged)
// ---------------------------------------------------------------------------
__global__ __launch_bounds__(256) void out_proj(const float* __restrict__ Att,
                                               const float* __restrict__ Wo,
                                               const float* __restrict__ Bo,
                                               float* __restrict__ Out) {
  __shared__ float xs[768];
  const int bid = blockIdx.x;
  const int rrow = bid / 3, cg = bid % 3;
  const int t = threadIdx.x;
  if (t < 192) *(f32x4*)&xs[t * 4] = *(const f32x4*)(Att + (size_t)rrow * 768 + t * 4);
  __syncthreads();
  const int c = cg * 256 + t;
  const float* wrow = Wo + (size_t)c * 768;
  float acc = 0.f;
#pragma unroll 8
  for (int jj = 0; jj < 192; ++jj) {
    f32x4 v = *(const f32x4*)(wrow + jj * 4);
    acc += v.x * xs[jj * 4] + v.y * xs[jj * 4 + 1] + v.z * xs[jj * 4 + 2] +
           v.w * xs[jj * 4 + 3];
  }
  acc += Bo[c];
  Out[(size_t)rrow * 768 + c] = acc;
}

// ---------------------------------------------------------------------------
extern "C" void kernel_launch(void* const* d_in, const int* in_sizes, int n_in,
                              void* d_out, int out_size, void* d_ws, size_t ws_size,
                              hipStream_t stream) {
  const float* X = (const float*)d_in[0];    // [8,8192,768] fp32
  const float* Wkv = (const float*)d_in[1];  // [1536,768] fp32
  const float* Wq = (const float*)d_in[2];   // [768,768] fp32
  const float* Wo = (const float*)d_in[3];   // [768,768] fp32
  const float* Bo = (const float*)d_in[4];   // [768] fp32
  float* Out = (float*)d_out;                // [8,4,768] fp32

  char* ws = (char*)d_ws;
  size_t off = 0;
  float* Q = (float*)(ws + off); off += 98304;
  float* Att = (float*)(ws + off); off += 98304;
  float* Mp = (float*)(ws + off); off += 384 * NSCH * 4;          //  49,152
  float* Lp = (float*)(ws + off); off += 384 * NSCH * 4;          //  49,152
  float* Op = (float*)(ws + off); off += (size_t)384 * NSCH * 64 * 4;  // 3,145,728
  u16* Wbf = (u16*)(ws + off); off += 2359296;
  u16* Xbf = (u16*)(ws + off); off += 100663296ull;
  const size_t tail = off;
  const size_t kvPerBatch = 2ull * 12 * 8192 * 64 * 2;  // 25,165,824 B

  int nb = 8;
  while (nb > 1 && tail + (size_t)nb * kvPerBatch > ws_size) nb >>= 1;
  const int groups = 8 / nb;
  u16* KV = (u16*)(ws + tail);

  hipLaunchKernelGGL(cvt_bf16, dim3(576), dim3(256), 0, stream, Wkv, Wbf,
                     1536 * 768 / 8);
  hipLaunchKernelGGL(cvt_bf16, dim3(24576), dim3(256), 0, stream, X, Xbf,
                     8 * 8192 * 768 / 8);
  hipLaunchKernelGGL(q_proj, dim3(96), dim3(256), 0, stream, X, Wq, Q);

  for (int g = 0; g < groups; ++g) {
    const int b0 = g * nb;
    hipLaunchKernelGGL(kv_gemm_mfma, dim3(nb * 768), dim3(256), 0, stream,
                       Xbf + (size_t)b0 * 8192 * 768, Wbf, KV, nb);
    hipLaunchKernelGGL(attn_part, dim3(nb * 12 * NSCH), dim3(256), 0, stream,
                       KV, Q, Mp, Lp, Op, b0, nb);
    hipLaunchKernelGGL(attn_combine, dim3(nb * 48), dim3(64), 0, stream,
                       Mp, Lp, Op, Att, b0);
  }
  hipLaunchKernelGGL(out_proj, dim3(96), dim3(256), 0, stream, Att, Wo, Bo, Out);
}

// Round 3
// 631.749 us; speedup vs baseline: 7.9226x; 1.0269x over previous
//
#include <hip/hip_runtime.h>

typedef unsigned short u16;
typedef __attribute__((ext_vector_type(8))) short short8;
typedef __attribute__((ext_vector_type(4))) float f32x4;
typedef __attribute__((ext_vector_type(8))) __bf16 bf16x8;

__device__ __forceinline__ float b2f(u16 u) {
  unsigned int i = ((unsigned int)u) << 16;
  return __builtin_bit_cast(float, i);
}
__device__ __forceinline__ u16 f2b(float f) {
  unsigned int i = __builtin_bit_cast(unsigned int, f);
  i += 0x7fffu + ((i >> 16) & 1u);   // RNE
  return (u16)(i >> 16);
}

// ---------------------------------------------------------------------------
// K0: fp32 -> bf16 conversion. (unchanged)
// ---------------------------------------------------------------------------
__global__ __launch_bounds__(256) void cvt_bf16(const float* __restrict__ in,
                                                u16* __restrict__ out, int n8) {
  int i = blockIdx.x * 256 + threadIdx.x;
  if (i >= n8) return;
  f32x4 v0 = *(const f32x4*)(in + (size_t)i * 8);
  f32x4 v1 = *(const f32x4*)(in + (size_t)i * 8 + 4);
  short8 o;
  o[0] = (short)f2b(v0.x); o[1] = (short)f2b(v0.y);
  o[2] = (short)f2b(v0.z); o[3] = (short)f2b(v0.w);
  o[4] = (short)f2b(v1.x); o[5] = (short)f2b(v1.y);
  o[6] = (short)f2b(v1.z); o[7] = (short)f2b(v1.w);
  *(short8*)(out + (size_t)i * 8) = o;
}

// ---------------------------------------------------------------------------
// K1: KV projection bf16 MFMA GEMM.
// CHANGED: T1 bijective XCD-aware blockIdx swizzle (grid % 8 == 0 always:
// grid = nb*768). 12 consecutive nt-blocks of one mt A-panel now land on the
// SAME XCD L2 -> A fetched ~once instead of ~4x.
// ---------------------------------------------------------------------------
__global__ __launch_bounds__(256) void kv_gemm_mfma(const u16* __restrict__ A,
                                                    const u16* __restrict__ B,
                                                    u16* __restrict__ KV, int nb) {
  __shared__ u16 As[128 * 32];
  __shared__ u16 Bs[128 * 32];
  const int tid = threadIdx.x;
  const int lane = tid & 63;
  const int w = tid >> 6;
  const int wr = w >> 1, wc = w & 1;
  const int fr = lane & 15;
  const int fq = lane >> 4;

  // T1: XCD swizzle. xcd = bid % 8 owns contiguous chunk of logical ids.
  const int bid0 = blockIdx.x;
  const int cpx = gridDim.x >> 3;               // blocks per XCD (grid % 8 == 0)
  const int bid = (bid0 & 7) * cpx + (bid0 >> 3);

  const int nt = bid % 12, mt = bid / 12;
  const int m0 = mt * 128, n0 = nt * 128;

  f32x4 acc[4][4] = {};

  for (int k0 = 0; k0 < 768; k0 += 32) {
#pragma unroll
    for (int i = 0; i < 2; ++i) {
      int c = w * 128 + i * 64 + lane;
      int row = c >> 2, q = c & 3;
      const u16* ga = A + (size_t)(m0 + row) * 768 + k0 + q * 8;
      const u16* gb = B + (size_t)(n0 + row) * 768 + k0 + q * 8;
      __builtin_amdgcn_global_load_lds(
          (const __attribute__((address_space(1))) void*)ga,
          (__attribute__((address_space(3))) void*)(As + (size_t)(w * 128 + i * 64) * 8),
          16, 0, 0);
      __builtin_amdgcn_global_load_lds(
          (const __attribute__((address_space(1))) void*)gb,
          (__attribute__((address_space(3))) void*)(Bs + (size_t)(w * 128 + i * 64) * 8),
          16, 0, 0);
    }
    __syncthreads();

    bf16x8 a[4], b[4];
#pragma unroll
    for (int m = 0; m < 4; ++m)
      a[m] = *(const bf16x8*)(As + (size_t)(wr * 64 + m * 16 + fr) * 32 + fq * 8);
#pragma unroll
    for (int n = 0; n < 4; ++n)
      b[n] = *(const bf16x8*)(Bs + (size_t)(wc * 64 + n * 16 + fr) * 32 + fq * 8);
#pragma unroll
    for (int m = 0; m < 4; ++m)
#pragma unroll
      for (int n = 0; n < 4; ++n)
        acc[m][n] = __builtin_amdgcn_mfma_f32_16x16x32_bf16(a[m], b[n], acc[m][n], 0, 0, 0);
    __syncthreads();
  }

  const int bl = m0 >> 13;
  const int sbase = (m0 & 8191) + wr * 64 + fq * 4;
#pragma unroll
  for (int n = 0; n < 4; ++n) {
    int f = n0 + wc * 64 + n * 16 + fr;
    int kvsel = f >= 768 ? 1 : 0;
    int h = (f >> 6) - kvsel * 12;
    int d = f & 63;
    u16* outp = KV + ((size_t)(kvsel * nb + bl) * 12 + h) * (8192 * 64) + d;
#pragma unroll
    for (int m = 0; m < 4; ++m) {
      int s = sbase + m * 16;
#pragma unroll
      for (int j = 0; j < 4; ++j)
        outp[(size_t)(s + j) * 64] = f2b(acc[m][n][j]);
    }
  }
}

// ---------------------------------------------------------------------------
// K2: Q projection (fp32), scale 0.125 folded in. (unchanged)
// ---------------------------------------------------------------------------
__global__ __launch_bounds__(256) void q_proj(const float* __restrict__ X,
                                              const float* __restrict__ Wq,
                                              float* __restrict__ Q) {
  __shared__ float xs[768];
  const int bid = blockIdx.x;
  const int rrow = bid / 3, cg = bid % 3;
  const int b = rrow >> 2, s = rrow & 3;
  const float* xrow = X + ((size_t)b * 8192 + s) * 768;
  const int t = threadIdx.x;
  if (t < 192) *(f32x4*)&xs[t * 4] = *(const f32x4*)(xrow + t * 4);
  __syncthreads();
  const int c = cg * 256 + t;
  const float* wrow = Wq + (size_t)c * 768;
  float acc = 0.f;
#pragma unroll 8
  for (int jj = 0; jj < 192; ++jj) {
    f32x4 v = *(const f32x4*)(wrow + jj * 4);
    acc += v.x * xs[jj * 4] + v.y * xs[jj * 4 + 1] + v.z * xs[jj * 4 + 2] +
           v.w * xs[jj * 4 + 3];
  }
  Q[(size_t)rrow * 768 + c] = acc * 0.125f;
}

// ---------------------------------------------------------------------------
// K3a: split-S attention partials. grid = nb*12*32, block 256.
// CHANGED: PV phase vectorized — wave splits 64 lanes into 8 y-subgroups x
// 8 d-chunks; short8 V loads (wave covers contiguous 1KB), 32 iters instead
// of 256 scalar loads; 3-round shfl_xor reduce over y-subgroups.
// ---------------------------------------------------------------------------
#define CHUNK 256
#define NSCH 32

__global__ __launch_bounds__(256) void attn_part(const u16* __restrict__ KV,
                                                 const float* __restrict__ Q,
                                                 float* __restrict__ Mp,
                                                 float* __restrict__ Lp,
                                                 float* __restrict__ Op,
                                                 int b0, int nb) {
  __shared__ float qsh[4][64];
  __shared__ float sc[4][CHUNK];
  const int tid = threadIdx.x;
  const int bid = blockIdx.x;
  const int ch = bid % NSCH;
  const int rem = bid / NSCH;
  const int h = rem % 12, bl = rem / 12;
  const int b = b0 + bl;

  qsh[tid >> 6][tid & 63] = Q[(size_t)(b * 4 + (tid >> 6)) * 768 + h * 64 + (tid & 63)];
  __syncthreads();

  const u16* Kb = KV + (size_t)(bl * 12 + h) * (8192 * 64) + (size_t)ch * CHUNK * 64;
  const u16* Vb = KV + (size_t)((nb + bl) * 12 + h) * (8192 * 64) + (size_t)ch * CHUNK * 64;

  // QK^T: thread tid owns position y = tid; K row read once, 4 dots.
  {
    const u16* kr = Kb + (size_t)tid * 64;
    float s0 = 0.f, s1 = 0.f, s2 = 0.f, s3 = 0.f;
#pragma unroll
    for (int jj = 0; jj < 8; ++jj) {
      short8 k8 = *(const short8*)(kr + jj * 8);
#pragma unroll
      for (int e = 0; e < 8; ++e) {
        float kv = b2f((u16)k8[e]);
        s0 += kv * qsh[0][jj * 8 + e];
        s1 += kv * qsh[1][jj * 8 + e];
        s2 += kv * qsh[2][jj * 8 + e];
        s3 += kv * qsh[3][jj * 8 + e];
      }
    }
    sc[0][tid] = s0; sc[1][tid] = s1; sc[2][tid] = s2; sc[3][tid] = s3;
  }
  __syncthreads();

  // chunk-local softmax for x = group g; partials written by lane 0.
  const int g = tid >> 6, lane = tid & 63;
  const int pidx = (((bl * 12 + h) * 4 + g) * NSCH) + ch;
  {
    float m4 = fmaxf(fmaxf(sc[g][lane], sc[g][lane + 64]),
                     fmaxf(sc[g][lane + 128], sc[g][lane + 192]));
#pragma unroll
    for (int off = 32; off; off >>= 1) m4 = fmaxf(m4, __shfl_xor(m4, off));
    float ls = 0.f;
#pragma unroll
    for (int i = 0; i < 4; ++i) {
      int y = lane + i * 64;
      float p = __expf(sc[g][y] - m4);
      sc[g][y] = p;
      ls += p;
    }
#pragma unroll
    for (int off = 32; off; off >>= 1) ls += __shfl_xor(ls, off);
    if (lane == 0) { Mp[pidx] = m4; Lp[pidx] = ls; }
  }
  __syncthreads();

  // partial PV, vectorized: wave g handles query g.
  {
    const int ys = lane >> 3, dc = lane & 7;
    float o8[8] = {0.f, 0.f, 0.f, 0.f, 0.f, 0.f, 0.f, 0.f};
#pragma unroll 4
    for (int y0 = 0; y0 < CHUNK; y0 += 8) {
      float p = sc[g][y0 + ys];
      short8 v8 = *(const short8*)(Vb + (size_t)(y0 + ys) * 64 + dc * 8);
#pragma unroll
      for (int e = 0; e < 8; ++e) o8[e] += p * b2f((u16)v8[e]);
    }
#pragma unroll
    for (int off = 32; off >= 8; off >>= 1)
#pragma unroll
      for (int e = 0; e < 8; ++e) o8[e] += __shfl_xor(o8[e], off);
    if (ys == 0) {
      f32x4 lo, hi;
      lo.x = o8[0]; lo.y = o8[1]; lo.z = o8[2]; lo.w = o8[3];
      hi.x = o8[4]; hi.y = o8[5]; hi.z = o8[6]; hi.w = o8[7];
      *(f32x4*)(Op + (size_t)pidx * 64 + dc * 8) = lo;
      *(f32x4*)(Op + (size_t)pidx * 64 + dc * 8 + 4) = hi;
    }
  }
}

// ---------------------------------------------------------------------------
// K3b: combine chunk partials. grid = nb*48, block 64. (unchanged)
// ---------------------------------------------------------------------------
__global__ __launch_bounds__(64) void attn_combine(const float* __restrict__ Mp,
                                                   const float* __restrict__ Lp,
                                                   const float* __restrict__ Op,
                                                   float* __restrict__ Att,
                                                   int b0) {
  const int p = blockIdx.x;            // (bl*12+h)*4 + x
  const int d = threadIdx.x;
  const int x = p & 3;
  const int h = (p >> 2) % 12;
  const int bl = p / 48;

  float M = -__builtin_inff();
#pragma unroll 8
  for (int ch = 0; ch < NSCH; ++ch) M = fmaxf(M, Mp[p * NSCH + ch]);
  float L = 0.f, O = 0.f;
#pragma unroll 8
  for (int ch = 0; ch < NSCH; ++ch) {
    float w = __expf(Mp[p * NSCH + ch] - M);
    L += Lp[p * NSCH + ch] * w;
    O += Op[(size_t)(p * NSCH + ch) * 64 + d] * w;
  }
  Att[(size_t)((b0 + bl) * 4 + x) * 768 + h * 64 + d] = O / L;
}

// ---------------------------------------------------------------------------
// K4: output projection + bias, fp32 output. (unchanged)
// ---------------------------------------------------------------------------
__global__ __launch_bounds__(256) void out_proj(const float* __restrict__ Att,
                                               const float* __restrict__ Wo,
                                               const float* __restrict__ Bo,
                                               float* __restrict__ Out) {
  __shared__ float xs[768];
  const int bid = blockIdx.x;
  const int rrow = bid / 3, cg = bid % 3;
  const int t = threadIdx.x;
  if (t < 192) *(f32x4*)&xs[t * 4] = *(const f32x4*)(Att + (size_t)rrow * 768 + t * 4);
  __syncthreads();
  const int c = cg * 256 + t;
  const float* wrow = Wo + (size_t)c * 768;
  float acc = 0.f;
#pragma unroll 8
  for (int jj = 0; jj < 192; ++jj) {
    f32x4 v = *(const f32x4*)(wrow + jj * 4);
    acc += v.x * xs[jj * 4] + v.y * xs[jj * 4 + 1] + v.z * xs[jj * 4 + 2] +
           v.w * xs[jj * 4 + 3];
  }
  acc += Bo[c];
  Out[(size_t)rrow * 768 + c] = acc;
}

// ---------------------------------------------------------------------------
extern "C" void kernel_launch(void* const* d_in, const int* in_sizes, int n_in,
                              void* d_out, int out_size, void* d_ws, size_t ws_size,
                              hipStream_t stream) {
  const float* X = (const float*)d_in[0];    // [8,8192,768] fp32
  const float* Wkv = (const float*)d_in[1];  // [1536,768] fp32
  const float* Wq = (const float*)d_in[2];   // [768,768] fp32
  const float* Wo = (const float*)d_in[3];   // [768,768] fp32
  const float* Bo = (const float*)d_in[4];   // [768] fp32
  float* Out = (float*)d_out;                // [8,4,768] fp32

  char* ws = (char*)d_ws;
  size_t off = 0;
  float* Q = (float*)(ws + off); off += 98304;
  float* Att = (float*)(ws + off); off += 98304;
  float* Mp = (float*)(ws + off); off += 384 * NSCH * 4;
  float* Lp = (float*)(ws + off); off += 384 * NSCH * 4;
  float* Op = (float*)(ws + off); off += (size_t)384 * NSCH * 64 * 4;
  u16* Wbf = (u16*)(ws + off); off += 2359296;
  u16* Xbf = (u16*)(ws + off); off += 100663296ull;
  const size_t tail = off;
  const size_t kvPerBatch = 2ull * 12 * 8192 * 64 * 2;  // 25,165,824 B

  int nb = 8;
  while (nb > 1 && tail + (size_t)nb * kvPerBatch > ws_size) nb >>= 1;
  const int groups = 8 / nb;
  u16* KV = (u16*)(ws + tail);

  hipLaunchKernelGGL(cvt_bf16, dim3(576), dim3(256), 0, stream, Wkv, Wbf,
                     1536 * 768 / 8);
  hipLaunchKernelGGL(cvt_bf16, dim3(24576), dim3(256), 0, stream, X, Xbf,
                     8 * 8192 * 768 / 8);
  hipLaunchKernelGGL(q_proj, dim3(96), dim3(256), 0, stream, X, Wq, Q);

  for (int g = 0; g < groups; ++g) {
    const int b0 = g * nb;
    hipLaunchKernelGGL(kv_gemm_mfma, dim3(nb * 768), dim3(256), 0, stream,
                       Xbf + (size_t)b0 * 8192 * 768, Wbf, KV, nb);
    hipLaunchKernelGGL(attn_part, dim3(nb * 12 * NSCH), dim3(256), 0, stream,
                       KV, Q, Mp, Lp, Op, b0, nb);
    hipLaunchKernelGGL(attn_combine, dim3(nb * 48), dim3(64), 0, stream,
                       Mp, Lp, Op, Att, b0);
  }
  hipLaunchKernelGGL(out_proj, dim3(96), dim3(256), 0, stream, Att, Wo, Bo, Out);
}

// Round 4
// 614.327 us; speedup vs baseline: 8.1473x; 1.0284x over previous
//
#include <hip/hip_runtime.h>

typedef unsigned short u16;
typedef __attribute__((ext_vector_type(8))) short short8;
typedef __attribute__((ext_vector_type(4))) float f32x4;
typedef __attribute__((ext_vector_type(8))) __bf16 bf16x8;

__device__ __forceinline__ float b2f(u16 u) {
  unsigned int i = ((unsigned int)u) << 16;
  return __builtin_bit_cast(float, i);
}
__device__ __forceinline__ u16 f2b(float f) {
  unsigned int i = __builtin_bit_cast(unsigned int, f);
  i += 0x7fffu + ((i >> 16) & 1u);   // RNE
  return (u16)(i >> 16);
}

// ---------------------------------------------------------------------------
// K0: fp32 -> bf16 conversion. (unchanged)
// ---------------------------------------------------------------------------
__global__ __launch_bounds__(256) void cvt_bf16(const float* __restrict__ in,
                                                u16* __restrict__ out, int n8) {
  int i = blockIdx.x * 256 + threadIdx.x;
  if (i >= n8) return;
  f32x4 v0 = *(const f32x4*)(in + (size_t)i * 8);
  f32x4 v1 = *(const f32x4*)(in + (size_t)i * 8 + 4);
  short8 o;
  o[0] = (short)f2b(v0.x); o[1] = (short)f2b(v0.y);
  o[2] = (short)f2b(v0.z); o[3] = (short)f2b(v0.w);
  o[4] = (short)f2b(v1.x); o[5] = (short)f2b(v1.y);
  o[6] = (short)f2b(v1.z); o[7] = (short)f2b(v1.w);
  *(short8*)(out + (size_t)i * 8) = o;
}

// ---------------------------------------------------------------------------
// K1: KV projection bf16 MFMA GEMM + T1 XCD swizzle. (unchanged from round 2)
// ---------------------------------------------------------------------------
__global__ __launch_bounds__(256) void kv_gemm_mfma(const u16* __restrict__ A,
                                                    const u16* __restrict__ B,
                                                    u16* __restrict__ KV, int nb) {
  __shared__ u16 As[128 * 32];
  __shared__ u16 Bs[128 * 32];
  const int tid = threadIdx.x;
  const int lane = tid & 63;
  const int w = tid >> 6;
  const int wr = w >> 1, wc = w & 1;
  const int fr = lane & 15;
  const int fq = lane >> 4;

  const int bid0 = blockIdx.x;
  const int cpx = gridDim.x >> 3;
  const int bid = (bid0 & 7) * cpx + (bid0 >> 3);

  const int nt = bid % 12, mt = bid / 12;
  const int m0 = mt * 128, n0 = nt * 128;

  f32x4 acc[4][4] = {};

  for (int k0 = 0; k0 < 768; k0 += 32) {
#pragma unroll
    for (int i = 0; i < 2; ++i) {
      int c = w * 128 + i * 64 + lane;
      int row = c >> 2, q = c & 3;
      const u16* ga = A + (size_t)(m0 + row) * 768 + k0 + q * 8;
      const u16* gb = B + (size_t)(n0 + row) * 768 + k0 + q * 8;
      __builtin_amdgcn_global_load_lds(
          (const __attribute__((address_space(1))) void*)ga,
          (__attribute__((address_space(3))) void*)(As + (size_t)(w * 128 + i * 64) * 8),
          16, 0, 0);
      __builtin_amdgcn_global_load_lds(
          (const __attribute__((address_space(1))) void*)gb,
          (__attribute__((address_space(3))) void*)(Bs + (size_t)(w * 128 + i * 64) * 8),
          16, 0, 0);
    }
    __syncthreads();

    bf16x8 a[4], b[4];
#pragma unroll
    for (int m = 0; m < 4; ++m)
      a[m] = *(const bf16x8*)(As + (size_t)(wr * 64 + m * 16 + fr) * 32 + fq * 8);
#pragma unroll
    for (int n = 0; n < 4; ++n)
      b[n] = *(const bf16x8*)(Bs + (size_t)(wc * 64 + n * 16 + fr) * 32 + fq * 8);
#pragma unroll
    for (int m = 0; m < 4; ++m)
#pragma unroll
      for (int n = 0; n < 4; ++n)
        acc[m][n] = __builtin_amdgcn_mfma_f32_16x16x32_bf16(a[m], b[n], acc[m][n], 0, 0, 0);
    __syncthreads();
  }

  const int bl = m0 >> 13;
  const int sbase = (m0 & 8191) + wr * 64 + fq * 4;
#pragma unroll
  for (int n = 0; n < 4; ++n) {
    int f = n0 + wc * 64 + n * 16 + fr;
    int kvsel = f >= 768 ? 1 : 0;
    int h = (f >> 6) - kvsel * 12;
    int d = f & 63;
    u16* outp = KV + ((size_t)(kvsel * nb + bl) * 12 + h) * (8192 * 64) + d;
#pragma unroll
    for (int m = 0; m < 4; ++m) {
      int s = sbase + m * 16;
#pragma unroll
      for (int j = 0; j < 4; ++j)
        outp[(size_t)(s + j) * 64] = f2b(acc[m][n][j]);
    }
  }
}

// ---------------------------------------------------------------------------
// K2: Q projection (fp32), scale 0.125 folded in. (unchanged)
// ---------------------------------------------------------------------------
__global__ __launch_bounds__(256) void q_proj(const float* __restrict__ X,
                                              const float* __restrict__ Wq,
                                              float* __restrict__ Q) {
  __shared__ float xs[768];
  const int bid = blockIdx.x;
  const int rrow = bid / 3, cg = bid % 3;
  const int b = rrow >> 2, s = rrow & 3;
  const float* xrow = X + ((size_t)b * 8192 + s) * 768;
  const int t = threadIdx.x;
  if (t < 192) *(f32x4*)&xs[t * 4] = *(const f32x4*)(xrow + t * 4);
  __syncthreads();
  const int c = cg * 256 + t;
  const float* wrow = Wq + (size_t)c * 768;
  float acc = 0.f;
#pragma unroll 8
  for (int jj = 0; jj < 192; ++jj) {
    f32x4 v = *(const f32x4*)(wrow + jj * 4);
    acc += v.x * xs[jj * 4] + v.y * xs[jj * 4 + 1] + v.z * xs[jj * 4 + 2] +
           v.w * xs[jj * 4 + 3];
  }
  Q[(size_t)rrow * 768 + c] = acc * 0.125f;
}

// ---------------------------------------------------------------------------
// K3a: split-S attention partials. grid = nb*12*32, block 256.
// CHANGED (QK^T): q held in 32 registers/thread (no LDS reads in inner loop);
// wave w covers y in [w*64, w*64+64) with lanes = 8 y-subgroups x 8 d-chunks;
// short8 coalesced K loads; 3-round shfl_xor reduce over d-chunks.
// ---------------------------------------------------------------------------
#define CHUNK 256
#define NSCH 32

__global__ __launch_bounds__(256) void attn_part(const u16* __restrict__ KV,
                                                 const float* __restrict__ Q,
                                                 float* __restrict__ Mp,
                                                 float* __restrict__ Lp,
                                                 float* __restrict__ Op,
                                                 int b0, int nb) {
  __shared__ float qsh[4][64];
  __shared__ float sc[4][CHUNK];
  const int tid = threadIdx.x;
  const int bid = blockIdx.x;
  const int ch = bid % NSCH;
  const int rem = bid / NSCH;
  const int h = rem % 12, bl = rem / 12;
  const int b = b0 + bl;

  qsh[tid >> 6][tid & 63] = Q[(size_t)(b * 4 + (tid >> 6)) * 768 + h * 64 + (tid & 63)];
  __syncthreads();

  const u16* Kb = KV + (size_t)(bl * 12 + h) * (8192 * 64) + (size_t)ch * CHUNK * 64;
  const u16* Vb = KV + (size_t)((nb + bl) * 12 + h) * (8192 * 64) + (size_t)ch * CHUNK * 64;

  const int wv = tid >> 6;           // wave 0..3
  const int lane = tid & 63;
  const int ys = lane >> 3, dc = lane & 7;

  // q slice into registers: q[x][dc*8 .. dc*8+8) for all 4 queries.
  float qr[4][8];
#pragma unroll
  for (int x = 0; x < 4; ++x) {
    f32x4 lo = *(const f32x4*)&qsh[x][dc * 8];
    f32x4 hi = *(const f32x4*)&qsh[x][dc * 8 + 4];
    qr[x][0] = lo.x; qr[x][1] = lo.y; qr[x][2] = lo.z; qr[x][3] = lo.w;
    qr[x][4] = hi.x; qr[x][5] = hi.y; qr[x][6] = hi.z; qr[x][7] = hi.w;
  }

  // QK^T: wave wv owns y in [wv*64, wv*64+64). 8 iters of 8 rows.
#pragma unroll
  for (int it = 0; it < 8; ++it) {
    const int y = wv * 64 + it * 8 + ys;
    short8 k8 = *(const short8*)(Kb + (size_t)y * 64 + dc * 8);
    float s0 = 0.f, s1 = 0.f, s2 = 0.f, s3 = 0.f;
#pragma unroll
    for (int e = 0; e < 8; ++e) {
      float kv = b2f((u16)k8[e]);
      s0 += kv * qr[0][e]; s1 += kv * qr[1][e];
      s2 += kv * qr[2][e]; s3 += kv * qr[3][e];
    }
#pragma unroll
    for (int off = 1; off <= 4; off <<= 1) {
      s0 += __shfl_xor(s0, off); s1 += __shfl_xor(s1, off);
      s2 += __shfl_xor(s2, off); s3 += __shfl_xor(s3, off);
    }
    if (dc == 0) {
      sc[0][y] = s0; sc[1][y] = s1; sc[2][y] = s2; sc[3][y] = s3;
    }
  }
  __syncthreads();

  // chunk-local softmax for x = wave index g; partials written by lane 0.
  const int g = wv;
  const int pidx = (((bl * 12 + h) * 4 + g) * NSCH) + ch;
  {
    float m4 = fmaxf(fmaxf(sc[g][lane], sc[g][lane + 64]),
                     fmaxf(sc[g][lane + 128], sc[g][lane + 192]));
#pragma unroll
    for (int off = 32; off; off >>= 1) m4 = fmaxf(m4, __shfl_xor(m4, off));
    float ls = 0.f;
#pragma unroll
    for (int i = 0; i < 4; ++i) {
      int y = lane + i * 64;
      float p = __expf(sc[g][y] - m4);
      sc[g][y] = p;
      ls += p;
    }
#pragma unroll
    for (int off = 32; off; off >>= 1) ls += __shfl_xor(ls, off);
    if (lane == 0) { Mp[pidx] = m4; Lp[pidx] = ls; }
  }
  __syncthreads();

  // partial PV, vectorized: wave g handles query g.
  {
    float o8[8] = {0.f, 0.f, 0.f, 0.f, 0.f, 0.f, 0.f, 0.f};
#pragma unroll 4
    for (int y0 = 0; y0 < CHUNK; y0 += 8) {
      float p = sc[g][y0 + ys];
      short8 v8 = *(const short8*)(Vb + (size_t)(y0 + ys) * 64 + dc * 8);
#pragma unroll
      for (int e = 0; e < 8; ++e) o8[e] += p * b2f((u16)v8[e]);
    }
#pragma unroll
    for (int off = 32; off >= 8; off >>= 1)
#pragma unroll
      for (int e = 0; e < 8; ++e) o8[e] += __shfl_xor(o8[e], off);
    if (ys == 0) {
      f32x4 lo, hi;
      lo.x = o8[0]; lo.y = o8[1]; lo.z = o8[2]; lo.w = o8[3];
      hi.x = o8[4]; hi.y = o8[5]; hi.z = o8[6]; hi.w = o8[7];
      *(f32x4*)(Op + (size_t)pidx * 64 + dc * 8) = lo;
      *(f32x4*)(Op + (size_t)pidx * 64 + dc * 8 + 4) = hi;
    }
  }
}

// ---------------------------------------------------------------------------
// K3b: combine chunk partials. grid = nb*48, block 64. (unchanged)
// ---------------------------------------------------------------------------
__global__ __launch_bounds__(64) void attn_combine(const float* __restrict__ Mp,
                                                   const float* __restrict__ Lp,
                                                   const float* __restrict__ Op,
                                                   float* __restrict__ Att,
                                                   int b0) {
  const int p = blockIdx.x;            // (bl*12+h)*4 + x
  const int d = threadIdx.x;
  const int x = p & 3;
  const int h = (p >> 2) % 12;
  const int bl = p / 48;

  float M = -__builtin_inff();
#pragma unroll 8
  for (int ch = 0; ch < NSCH; ++ch) M = fmaxf(M, Mp[p * NSCH + ch]);
  float L = 0.f, O = 0.f;
#pragma unroll 8
  for (int ch = 0; ch < NSCH; ++ch) {
    float w = __expf(Mp[p * NSCH + ch] - M);
    L += Lp[p * NSCH + ch] * w;
    O += Op[(size_t)(p * NSCH + ch) * 64 + d] * w;
  }
  Att[(size_t)((b0 + bl) * 4 + x) * 768 + h * 64 + d] = O / L;
}

// ---------------------------------------------------------------------------
// K4: output projection + bias, fp32 output. (unchanged)
// ---------------------------------------------------------------------------
__global__ __launch_bounds__(256) void out_proj(const float* __restrict__ Att,
                                               const float* __restrict__ Wo,
                                               const float* __restrict__ Bo,
                                               float* __restrict__ Out) {
  __shared__ float xs[768];
  const int bid = blockIdx.x;
  const int rrow = bid / 3, cg = bid % 3;
  const int t = threadIdx.x;
  if (t < 192) *(f32x4*)&xs[t * 4] = *(const f32x4*)(Att + (size_t)rrow * 768 + t * 4);
  __syncthreads();
  const int c = cg * 256 + t;
  const float* wrow = Wo + (size_t)c * 768;
  float acc = 0.f;
#pragma unroll 8
  for (int jj = 0; jj < 192; ++jj) {
    f32x4 v = *(const f32x4*)(wrow + jj * 4);
    acc += v.x * xs[jj * 4] + v.y * xs[jj * 4 + 1] + v.z * xs[jj * 4 + 2] +
           v.w * xs[jj * 4 + 3];
  }
  acc += Bo[c];
  Out[(size_t)rrow * 768 + c] = acc;
}

// ---------------------------------------------------------------------------
extern "C" void kernel_launch(void* const* d_in, const int* in_sizes, int n_in,
                              void* d_out, int out_size, void* d_ws, size_t ws_size,
                              hipStream_t stream) {
  const float* X = (const float*)d_in[0];    // [8,8192,768] fp32
  const float* Wkv = (const float*)d_in[1];  // [1536,768] fp32
  const float* Wq = (const float*)d_in[2];   // [768,768] fp32
  const float* Wo = (const float*)d_in[3];   // [768,768] fp32
  const float* Bo = (const float*)d_in[4];   // [768] fp32
  float* Out = (float*)d_out;                // [8,4,768] fp32

  char* ws = (char*)d_ws;
  size_t off = 0;
  float* Q = (float*)(ws + off); off += 98304;
  float* Att = (float*)(ws + off); off += 98304;
  float* Mp = (float*)(ws + off); off += 384 * NSCH * 4;
  float* Lp = (float*)(ws + off); off += 384 * NSCH * 4;
  float* Op = (float*)(ws + off); off += (size_t)384 * NSCH * 64 * 4;
  u16* Wbf = (u16*)(ws + off); off += 2359296;
  u16* Xbf = (u16*)(ws + off); off += 100663296ull;
  const size_t tail = off;
  const size_t kvPerBatch = 2ull * 12 * 8192 * 64 * 2;  // 25,165,824 B

  int nb = 8;
  while (nb > 1 && tail + (size_t)nb * kvPerBatch > ws_size) nb >>= 1;
  const int groups = 8 / nb;
  u16* KV = (u16*)(ws + tail);

  hipLaunchKernelGGL(cvt_bf16, dim3(576), dim3(256), 0, stream, Wkv, Wbf,
                     1536 * 768 / 8);
  hipLaunchKernelGGL(cvt_bf16, dim3(24576), dim3(256), 0, stream, X, Xbf,
                     8 * 8192 * 768 / 8);
  hipLaunchKernelGGL(q_proj, dim3(96), dim3(256), 0, stream, X, Wq, Q);

  for (int g = 0; g < groups; ++g) {
    const int b0 = g * nb;
    hipLaunchKernelGGL(kv_gemm_mfma, dim3(nb * 768), dim3(256), 0, stream,
                       Xbf + (size_t)b0 * 8192 * 768, Wbf, KV, nb);
    hipLaunchKernelGGL(attn_part, dim3(nb * 12 * NSCH), dim3(256), 0, stream,
                       KV, Q, Mp, Lp, Op, b0, nb);
    hipLaunchKernelGGL(attn_combine, dim3(nb * 48), dim3(64), 0, stream,
                       Mp, Lp, Op, Att, b0);
  }
  hipLaunchKernelGGL(out_proj, dim3(96), dim3(256), 0, stream, Att, Wo, Bo, Out);
}